// Round 14
// baseline (79.479 us; speedup 1.0000x reference)
//
#include <hip/hip_runtime.h>

// VesselIntensitySynth: flip(labels) -> LUT gather -> {intensity plane, 3-way onehot}
// Output layout: d_out = [scaling (D*H*W)] ++ [onehot plane0..2 (3*D*H*W)], float32.
//
// Tuning history:
//  - nontemporal stores: 2x REGRESSION (129.8us) — gfx950 L2 write-combining
//    path is faster for streaming stores. Regular stores only.
//  - 8 vox/thread, 32B lane stride stores: REGRESSION (70.4us).
//  - LUT width b64 vs b32: neutral — LDS not limiting.
//  - plane-major store bursts (r11): neutral (67.8 vs 65.9us) — memory
//    controller already reorders per-wave stream interleave.
//  - This version: PLANE-SPLIT blocks. Block b -> plane b&3, slice b>>2.
//    Each wave: 1 read stream + 1 write stream (memset-like). Labels are
//    issued 4x but 64MiB fits the 256MiB die-level L3 -> HBM FETCH should
//    stay ~67MB. Tests whether DRAM stream count is the residual limiter.

constexpr int VOXELS = 256 * 256 * 256;

typedef int   iv4 __attribute__((ext_vector_type(4)));
typedef float fv4 __attribute__((ext_vector_type(4)));

// ---------------- host-side Threefry-2x32 (JAX-compatible) ----------------
static inline unsigned rotl32(unsigned x, unsigned r) {
    return (x << r) | (x >> (32u - r));
}

static void threefry2x32(unsigned k0, unsigned k1, unsigned c0, unsigned c1,
                         unsigned* o0, unsigned* o1) {
    const unsigned rotA[4] = {13u, 15u, 26u, 6u};
    const unsigned rotB[4] = {17u, 29u, 16u, 24u};
    unsigned ks[3] = {k0, k1, k0 ^ k1 ^ 0x1BD11BDAu};
    unsigned x0 = c0 + ks[0];
    unsigned x1 = c1 + ks[1];
    for (int g = 0; g < 5; ++g) {
        const unsigned* rot = ((g & 1) == 0) ? rotA : rotB;
        for (int r = 0; r < 4; ++r) {
            x0 += x1;
            x1 = rotl32(x1, rot[r]);
            x1 ^= x0;
        }
        x0 += ks[(g + 1) % 3];
        x1 += ks[(g + 2) % 3] + (unsigned)(g + 1);
    }
    *o0 = x0;
    *o1 = x1;
}

// flips = bernoulli(jax.random.key(1), 0.5, (3,)) under the PARTITIONABLE
// threefry scheme (JAX default): bits_i = out0 ^ out1 of
// threefry2x32(key=(0,1), (0, i)); flip_i = top bit of bits_i == 0.
static int jax_flip_bit(unsigned i) {
    unsigned o0, o1;
    threefry2x32(0u, 1u, 0u, i, &o0, &o1);
    return (((o0 ^ o1) >> 31) == 0u) ? 1 : 0;
}

// ---------------- device kernel ----------------
__global__ __launch_bounds__(256) void VesselIntensitySynth_kernel(
    const int* __restrict__ labels,
    const float* __restrict__ ilut,
    const int* __restrict__ clut,
    float* __restrict__ out,
    const int f0, const int f1, const int f2)
{
    // Packed LUT in LDS: fp32 intensity with class in low 2 mantissa bits
    // (<= 3 ulp perturbation; threshold 4.2e-2). 512 * 4B = 2 KiB.
    __shared__ unsigned lut[512];
    for (int i = threadIdx.x; i < 512; i += 256) {
        const unsigned ib = __float_as_uint(ilut[i]);
        lut[i] = (ib & ~3u) | (unsigned)clut[i];
    }
    __syncthreads();

    const int plane    = blockIdx.x & 3;   // which output plane this block writes
    const int sliceblk = blockIdx.x >> 2;  // 0..4095, which 4096-voxel slice
    const int wave     = threadIdx.x >> 6; // 0..3
    const int lane     = threadIdx.x & 63;

    // wave owns 1024 contiguous voxels of ONE plane = 4 h-rows x 256
    const int vbase = (sliceblk << 12) + (wave << 10);
    const int w  = lane << 2;              // 0..252
    const int h0 = (vbase >> 8) & 255;     // multiple of 4
    const int d  = vbase >> 16;

    const int sd = f0 ? (255 - d) : d;
    const int sw = f2 ? (252 - w) : w;
    const int sdw = (sd << 16) | sw;

    // ---- phase 1: 4 independent label loads (read-stream MLP) ----
    iv4 labs[4];
#pragma unroll
    for (int j = 0; j < 4; ++j) {
        const int sh = f1 ? (255 - (h0 + j)) : (h0 + j);
        labs[j] = *reinterpret_cast<const iv4*>(labels + (sdw | (sh << 8)));
    }

    // ---- phase 2: LDS gather (16 packed words) ----
    unsigned pw[4][4];
#pragma unroll
    for (int j = 0; j < 4; ++j) {
        iv4 lab = labs[j];
        if (f2) {
            int tmp = lab.x; lab.x = lab.w; lab.w = tmp;
            tmp = lab.y;     lab.y = lab.z; lab.z = tmp;
        }
        pw[j][0] = lut[lab.x];
        pw[j][1] = lut[lab.y];
        pw[j][2] = lut[lab.z];
        pw[j][3] = lut[lab.w];
    }

    // ---- phase 3: single-plane stores (4x 1KiB contiguous bursts) ----
    float* p = out + (size_t)plane * VOXELS + vbase + w;
    if (plane == 0) {
        // intensity plane: clear class bits
#pragma unroll
        for (int j = 0; j < 4; ++j) {
            fv4 s;
            s.x = __uint_as_float(pw[j][0] & ~3u);
            s.y = __uint_as_float(pw[j][1] & ~3u);
            s.z = __uint_as_float(pw[j][2] & ~3u);
            s.w = __uint_as_float(pw[j][3] & ~3u);
            *reinterpret_cast<fv4*>(p + (j << 8)) = s;
        }
    } else {
        const unsigned cls = (unsigned)(plane - 1);
#pragma unroll
        for (int j = 0; j < 4; ++j) {
            fv4 s;
            s.x = ((pw[j][0] & 3u) == cls) ? 1.0f : 0.0f;
            s.y = ((pw[j][1] & 3u) == cls) ? 1.0f : 0.0f;
            s.z = ((pw[j][2] & 3u) == cls) ? 1.0f : 0.0f;
            s.w = ((pw[j][3] & 3u) == cls) ? 1.0f : 0.0f;
            *reinterpret_cast<fv4*>(p + (j << 8)) = s;
        }
    }
}

extern "C" void kernel_launch(void* const* d_in, const int* in_sizes, int n_in,
                              void* d_out, int out_size, void* d_ws, size_t ws_size,
                              hipStream_t stream) {
    const int*   labels = (const int*)  d_in[0];
    const float* ilut   = (const float*)d_in[1];
    const int*   clut   = (const int*)  d_in[2];
    float*       out    = (float*)      d_out;

    const int f0 = jax_flip_bit(0u);
    const int f1 = jax_flip_bit(1u);
    const int f2 = jax_flip_bit(2u);

    const int threads = 256;
    // 4 planes x (VOXELS / 16 voxels-per-thread / 256 threads) slices
    const int blocks  = 4 * (VOXELS / 16 / threads);   // 16384
    VesselIntensitySynth_kernel<<<blocks, threads, 0, stream>>>(
        labels, ilut, clut, out, f0, f1, f2);
}

// Round 15
// 71.542 us; speedup vs baseline: 1.1109x; 1.1109x over previous
//
#include <hip/hip_runtime.h>

// VesselIntensitySynth: flip(labels) -> LUT gather -> {intensity plane, 3-way onehot}
// Output layout: d_out = [scaling (D*H*W)] ++ [onehot plane0..2 (3*D*H*W)], float32.
//
// Tuning ledger:
//  - nontemporal stores: 2x REGRESSION (129.8us) — L2 write-combining path wins.
//  - 8 vox/thread, 32B lane-stride stores: REGRESSION (70.4us).
//  - LUT width b128/b64/b32: neutral — LDS not limiting. Packed b32 kept.
//  - plane-major store bursts: neutral (67.8) — MC reorders streams anyway.
//  - plane-split blocks (1R+1W per wave, 4x read requests): REGRESSION (79.5us).
//  - This version: grid-stride SOFTWARE PIPELINE. 2048 blocks (8/CU), 8
//    tiles/thread, next label load issued before current tile's stores ->
//    per-wave load-latency hiding on top of TLP. Store shape = r6's proven
//    4 vox/thread interleaved planes, 16B/lane contiguous.

constexpr int VOXELS = 256 * 256 * 256;

typedef int   iv4 __attribute__((ext_vector_type(4)));
typedef float fv4 __attribute__((ext_vector_type(4)));

// ---------------- host-side Threefry-2x32 (JAX-compatible) ----------------
static inline unsigned rotl32(unsigned x, unsigned r) {
    return (x << r) | (x >> (32u - r));
}

static void threefry2x32(unsigned k0, unsigned k1, unsigned c0, unsigned c1,
                         unsigned* o0, unsigned* o1) {
    const unsigned rotA[4] = {13u, 15u, 26u, 6u};
    const unsigned rotB[4] = {17u, 29u, 16u, 24u};
    unsigned ks[3] = {k0, k1, k0 ^ k1 ^ 0x1BD11BDAu};
    unsigned x0 = c0 + ks[0];
    unsigned x1 = c1 + ks[1];
    for (int g = 0; g < 5; ++g) {
        const unsigned* rot = ((g & 1) == 0) ? rotA : rotB;
        for (int r = 0; r < 4; ++r) {
            x0 += x1;
            x1 = rotl32(x1, rot[r]);
            x1 ^= x0;
        }
        x0 += ks[(g + 1) % 3];
        x1 += ks[(g + 2) % 3] + (unsigned)(g + 1);
    }
    *o0 = x0;
    *o1 = x1;
}

// flips = bernoulli(jax.random.key(1), 0.5, (3,)) under the PARTITIONABLE
// threefry scheme (JAX default): bits_i = out0 ^ out1 of
// threefry2x32(key=(0,1), (0, i)); flip_i = top bit of bits_i == 0.
static int jax_flip_bit(unsigned i) {
    unsigned o0, o1;
    threefry2x32(0u, 1u, 0u, i, &o0, &o1);
    return (((o0 ^ o1) >> 31) == 0u) ? 1 : 0;
}

// ---------------- device kernel ----------------
__global__ __launch_bounds__(256) void VesselIntensitySynth_kernel(
    const int* __restrict__ labels,
    const float* __restrict__ ilut,
    const int* __restrict__ clut,
    float* __restrict__ out,
    const int f0, const int f1, const int f2)
{
    // Packed LUT in LDS: fp32 intensity with class in low 2 mantissa bits
    // (<= 3 ulp perturbation; threshold 4.2e-2). 512 * 4B = 2 KiB.
    __shared__ unsigned lut[512];
    for (int i = threadIdx.x; i < 512; i += 256) {
        const unsigned ib = __float_as_uint(ilut[i]);
        lut[i] = (ib & ~3u) | (unsigned)clut[i];
    }
    __syncthreads();

    // 2048 blocks x 256 threads = 524288 threads; each owns 8 tiles of 4 vox.
    // Grid stride in voxels = 524288*4 = 1<<21 -> only d changes (+32/iter);
    // (w,h) are iteration-invariant.
    const int t0 = blockIdx.x * 256 + threadIdx.x;
    const int v0 = t0 << 2;
    const int w  = v0 & 255;
    const int h  = (v0 >> 8) & 255;
    const int d0 = v0 >> 16;              // 0..31

    const int sh  = f1 ? (255 - h) : h;
    const int sw  = f2 ? (252 - w) : w;
    const int shw = (sh << 8) | sw;

    // src address for iteration k (d = d0 + 32k)
    auto src_of = [&](int k) -> const iv4* {
        const int d  = d0 + (k << 5);
        const int sd = f0 ? (255 - d) : d;
        return reinterpret_cast<const iv4*>(labels + ((sd << 16) | shw));
    };

    iv4 cur = *src_of(0);

#pragma unroll
    for (int k = 0; k < 8; ++k) {
        iv4 nxt;
        if (k < 7) nxt = *src_of(k + 1);   // prefetch: in flight during stores

        iv4 lab = cur;
        if (f2) {
            int tmp = lab.x; lab.x = lab.w; lab.w = tmp;
            tmp = lab.y;     lab.y = lab.z; lab.z = tmp;
        }

        const unsigned p0 = lut[lab.x];
        const unsigned p1 = lut[lab.y];
        const unsigned p2 = lut[lab.z];
        const unsigned p3 = lut[lab.w];

        const int v = v0 + (k << 21);      // output voxel base this iter
        fv4 s;

        // plane 0: intensity (clear class bits)
        s.x = __uint_as_float(p0 & ~3u);
        s.y = __uint_as_float(p1 & ~3u);
        s.z = __uint_as_float(p2 & ~3u);
        s.w = __uint_as_float(p3 & ~3u);
        *reinterpret_cast<fv4*>(out + v) = s;

        // planes 1..3: onehot(class)
        float* oh = out + VOXELS + v;
        s.x = ((p0 & 3u) == 0u) ? 1.0f : 0.0f;
        s.y = ((p1 & 3u) == 0u) ? 1.0f : 0.0f;
        s.z = ((p2 & 3u) == 0u) ? 1.0f : 0.0f;
        s.w = ((p3 & 3u) == 0u) ? 1.0f : 0.0f;
        *reinterpret_cast<fv4*>(oh) = s;

        s.x = ((p0 & 3u) == 1u) ? 1.0f : 0.0f;
        s.y = ((p1 & 3u) == 1u) ? 1.0f : 0.0f;
        s.z = ((p2 & 3u) == 1u) ? 1.0f : 0.0f;
        s.w = ((p3 & 3u) == 1u) ? 1.0f : 0.0f;
        *reinterpret_cast<fv4*>(oh + VOXELS) = s;

        s.x = ((p0 & 3u) == 2u) ? 1.0f : 0.0f;
        s.y = ((p1 & 3u) == 2u) ? 1.0f : 0.0f;
        s.z = ((p2 & 3u) == 2u) ? 1.0f : 0.0f;
        s.w = ((p3 & 3u) == 2u) ? 1.0f : 0.0f;
        *reinterpret_cast<fv4*>(oh + 2 * VOXELS) = s;

        cur = nxt;
    }
}

extern "C" void kernel_launch(void* const* d_in, const int* in_sizes, int n_in,
                              void* d_out, int out_size, void* d_ws, size_t ws_size,
                              hipStream_t stream) {
    const int*   labels = (const int*)  d_in[0];
    const float* ilut   = (const float*)d_in[1];
    const int*   clut   = (const int*)  d_in[2];
    float*       out    = (float*)      d_out;

    const int f0 = jax_flip_bit(0u);
    const int f1 = jax_flip_bit(1u);
    const int f2 = jax_flip_bit(2u);

    const int threads = 256;
    const int blocks  = 2048;   // 8 blocks/CU on 256 CUs; 8 tiles/thread
    VesselIntensitySynth_kernel<<<blocks, threads, 0, stream>>>(
        labels, ilut, clut, out, f0, f1, f2);
}